// Round 1
// baseline (112.244 us; speedup 1.0000x reference)
//
#include <hip/hip_runtime.h>

// Truncated path signature, trunc=4, D=8, B=128, S=512 (shapes fixed by setup_inputs).
// One block per batch, 512 threads (8 waves).
// State ownership:
//   level1 (8)    : acc1 in regs of tid<8, mirrored in LDS s1L (double-buffered)
//   level2 (64)   : acc2 in regs of tid<64, mirrored in LDS s2L (double-buffered)
//   level3 (512)  : acc3 in regs, elem n = tid (reader of s3[n] for level-4 IS its owner)
//   level4 (4096) : acc4[8] in regs, elems m = 8*tid + d
// dx increments precomputed into LDS once -> no global latency inside the scan loop.
// One __syncthreads per step (double-buffered s1/s2).

constexpr int Bc = 128;
constexpr int Sc = 512;
constexpr int Dc = 8;
constexpr int Tc = Sc - 1;                         // 511 increments
constexpr int OUT_STRIDE = 8 + 64 + 512 + 4096;    // 4680

__global__ __launch_bounds__(512)
void sig_kernel(const float* __restrict__ path, float* __restrict__ out) {
    const int b   = blockIdx.x;
    const int tid = threadIdx.x;

    __shared__ float dxAll[Tc * Dc];   // 4088 floats = 16.0 KiB
    __shared__ float s1L[2][8];
    __shared__ float s2L[2][64];

    const float* prow = path + (size_t)b * Sc * Dc;

    // Precompute all segment increments: dxAll[t*8+j] = path[b,t+1,j] - path[b,t,j]
    for (int n = tid; n < Tc * Dc; n += 512) {
        dxAll[n] = prow[n + 8] - prow[n];
    }
    if (tid < 8)  s1L[0][tid] = 0.f;
    if (tid < 64) s2L[0][tid] = 0.f;

    float acc4[8];
#pragma unroll
    for (int d = 0; d < 8; ++d) acc4[d] = 0.f;
    float acc3 = 0.f, acc2 = 0.f, acc1 = 0.f;

    // digit indices of this thread's level-3 element n = tid = (a,b,c)
    const int aa = tid >> 6;          // a (wave-uniform)
    const int bbি = 0;                 // placeholder removed below
    (void)bbি;
    const int bb = (tid >> 3) & 7;    // b
    const int cc = tid & 7;           // c

    __syncthreads();

    int pb = 0;
    for (int t = 0; t < Tc; ++t) {
        const int nb = pb ^ 1;
        const float* drow = &dxAll[t * 8];

        // whole dx row (broadcast b128 reads), plus per-digit picks
        float4 lo = *(const float4*)(drow);
        float4 hi = *(const float4*)(drow + 4);
        float da = drow[aa];
        float db = drow[bb];
        float dc = drow[cc];

        float s2v = s2L[pb][tid >> 3];   // s2[a*8+b]
        float s1v = s1L[pb][tid >> 6];   // s1[a]

        float e  = db * dc;
        float hc = 0.5f * dc;
        float v  = s1v * (1.f / 6.f) + da * (1.f / 24.f);
        float K  = acc3 + s2v * hc + e * v;   // uses OLD acc3

        // level 4: acc4[d] += dx[d] * K   (elems m = 8*tid + d)
        acc4[0] = fmaf(lo.x, K, acc4[0]);
        acc4[1] = fmaf(lo.y, K, acc4[1]);
        acc4[2] = fmaf(lo.z, K, acc4[2]);
        acc4[3] = fmaf(lo.w, K, acc4[3]);
        acc4[4] = fmaf(hi.x, K, acc4[4]);
        acc4[5] = fmaf(hi.y, K, acc4[5]);
        acc4[6] = fmaf(hi.z, K, acc4[6]);
        acc4[7] = fmaf(hi.w, K, acc4[7]);

        // level 3: new3 = s3 + s2[ab]*dx[c] + s1[a]*dx[b]dx[c]/2 + dx[a]dx[b]dx[c]/6
        acc3 = acc3 + s2v * dc + e * (0.5f * s1v) + (e * da) * (1.f / 6.f);

        // level 2 / level 1 (owners only), write next buffer
        if (tid < 64) {
            float s1v2 = s1L[pb][tid >> 3];          // s1[a2], a2 = tid>>3
            acc2 = acc2 + s1v2 * dc + 0.5f * e;      // + dx[a2]dx[b2]/2 (= e/2 here)
            if (tid < 8) acc1 += dc;                 // dc == dx[tid] for tid<8
            s2L[nb][tid] = acc2;
            if (tid < 8) s1L[nb][tid] = acc1;
        }
        __syncthreads();
        pb = nb;
    }

    // write out: [s1 (8) | s2 (64) | s3 (512) | s4 (4096)]
    float* ob = out + (size_t)b * OUT_STRIDE;
    if (tid < 8)  ob[tid] = acc1;
    if (tid < 64) ob[8 + tid] = acc2;
    ob[72 + tid] = acc3;
    float4 v0 = make_float4(acc4[0], acc4[1], acc4[2], acc4[3]);
    float4 v1 = make_float4(acc4[4], acc4[5], acc4[6], acc4[7]);
    float4* o4 = (float4*)(ob + 584 + 8 * tid);
    o4[0] = v0;
    o4[1] = v1;
}

extern "C" void kernel_launch(void* const* d_in, const int* in_sizes, int n_in,
                              void* d_out, int out_size, void* d_ws, size_t ws_size,
                              hipStream_t stream) {
    const float* path = (const float*)d_in[0];
    float* out = (float*)d_out;
    // shapes fixed by setup_inputs: B=128, S=512, D=8, trunc=4
    sig_kernel<<<dim3(Bc), dim3(512), 0, stream>>>(path, out);
}

// Round 2
// 46.885 us; speedup vs baseline: 2.3940x; 2.3940x over previous
//
#include <hip/hip_runtime.h>

// Truncated path signature, trunc=4, D=8, B=128, S=512.
// Two-phase associative scan over time:
//   Phase 1: 128 batches x 8 chunks of 64 steps, one block each (512 thr),
//            BARRIER-FREE Chen recurrence (all needed state is thread-local),
//            chunk signature -> ws.
//   Phase 2: 128 blocks fold the 8 chunk signatures (Chen product), also
//            barrier-free, -> d_out.
// Thread ownership (tid in [0,512)): digits aa=tid>>6, bb=(tid>>3)&7, cc=tid&7.
//   level3[tid] and level4[8*tid+d] in regs; level1/level2 outputs tracked
//   redundantly per-thread (s1c for tid<8, s2[bb,cc] for tid<64).

constexpr int Bc = 128, Sc = 512, Tc = 511;
constexpr int NCH = 8, CH = 64;             // 8 chunks; 64 steps (last chunk 63)
constexpr int SIGSZ = 8 + 64 + 512 + 4096;  // 4680 floats per signature

// ---------------- Phase 1: per-chunk signature ----------------
__global__ __launch_bounds__(512, 8)
void sig_chunk(const float* __restrict__ path, float* __restrict__ ws) {
    const int blk = blockIdx.x;
    const int b   = blk >> 3;          // batch
    const int c   = blk & 7;           // chunk
    const int tid = threadIdx.x;
    const int t0  = c * CH;
    const int nst = min(CH, Tc - t0);  // 64, except 63 for last chunk

    __shared__ float dxs[CH * 8];      // 2 KiB
    const float* prow = path + ((size_t)b * Sc + t0) * 8;
    if (tid < nst * 8) dxs[tid] = prow[tid + 8] - prow[tid];
    __syncthreads();                   // only barrier in this kernel

    const int aa = tid >> 6, bb = (tid >> 3) & 7, cc = tid & 7;

    float acc4[8] = {0.f,0.f,0.f,0.f,0.f,0.f,0.f,0.f};
    float acc3 = 0.f, s2ab = 0.f, acc2 = 0.f;
    float s1a = 0.f, s1b = 0.f, s1c = 0.f;

#pragma unroll 2
    for (int t = 0; t < nst; ++t) {
        const float* r = &dxs[t * 8];
        float4 lo = *(const float4*)r;
        float4 hi = *(const float4*)(r + 4);
        float da = r[aa], db = r[bb], dc = r[cc];

        float e = db * dc;
        float K = acc3 + s2ab * (0.5f * dc)
                       + e * fmaf(s1a, 1.f/6.f, da * (1.f/24.f));

        acc4[0] = fmaf(lo.x, K, acc4[0]);
        acc4[1] = fmaf(lo.y, K, acc4[1]);
        acc4[2] = fmaf(lo.z, K, acc4[2]);
        acc4[3] = fmaf(lo.w, K, acc4[3]);
        acc4[4] = fmaf(hi.x, K, acc4[4]);
        acc4[5] = fmaf(hi.y, K, acc4[5]);
        acc4[6] = fmaf(hi.z, K, acc4[6]);
        acc4[7] = fmaf(hi.w, K, acc4[7]);

        // level-3: += s2[ab]*dc + s1[a]*db*dc/2 + da*db*dc/6
        acc3 = acc3 + s2ab * dc + e * fmaf(0.5f, s1a, da * (1.f/6.f));
        // level-2 output elem (bb,cc): += s1[b]*dc + db*dc/2
        acc2 = fmaf(s1b, dc, fmaf(0.5f, e, acc2));
        // level-2 pick (aa,bb): += s1[a]*db + da*db/2
        s2ab = fmaf(s1a, db, fmaf(0.5f * da, db, s2ab));
        s1a += da; s1b += db; s1c += dc;
    }

    float* o = ws + (size_t)blk * SIGSZ;
    if (tid < 8)  o[tid] = s1c;        // level1[tid] (cc==tid)
    if (tid < 64) o[8 + tid] = acc2;   // level2[tid] ((bb,cc)==tid)
    o[72 + tid] = acc3;
    *(float4*)(o + 584 + 8 * tid)     = make_float4(acc4[0], acc4[1], acc4[2], acc4[3]);
    *(float4*)(o + 584 + 8 * tid + 4) = make_float4(acc4[4], acc4[5], acc4[6], acc4[7]);
}

// ---------------- Phase 2: fold chunk signatures ----------------
// x := x (x) y repeatedly; starting from x = 0 (identity): fold chunks 0..7.
__global__ __launch_bounds__(512)
void sig_combine(const float* __restrict__ ws, float* __restrict__ out) {
    const int b = blockIdx.x, tid = threadIdx.x;
    const int aa = tid >> 6, bb = (tid >> 3) & 7, cc = tid & 7;

    float x4[8] = {0.f,0.f,0.f,0.f,0.f,0.f,0.f,0.f};
    float x3 = 0.f, x2ab = 0.f, x2own = 0.f;
    float x1a = 0.f, x1b = 0.f, x1c = 0.f;

    for (int c = 0; c < NCH; ++c) {
        const float* y = ws + ((size_t)(b * NCH + c)) * SIGSZ;

        float4 y1lo = *(const float4*)y;
        float4 y1hi = *(const float4*)(y + 4);
        float y1a = y[aa], y1b = y[bb], y1c = y[cc];
        float y2ab = y[8 + 8 * aa + bb];
        float y2bc = y[8 + 8 * bb + cc];
        const float* y2r = y + 8 + 8 * cc;        // y2[cc, d]
        float4 y2lo = *(const float4*)y2r;
        float4 y2hi = *(const float4*)(y2r + 4);
        const float* y3r = y + 72 + 8 * (tid & 63); // y3[bb,cc,d]
        float4 y3lo = *(const float4*)y3r;
        float4 y3hi = *(const float4*)(y3r + 4);
        float y3own = y[72 + tid];
        const float* y4r = y + 584 + 8 * tid;
        float4 y4lo = *(const float4*)y4r;
        float4 y4hi = *(const float4*)(y4r + 4);

        // new4[abcd] = x4 + x3[abc]y1[d] + x2[ab]y2[cd] + x1[a]y3[bcd] + y4
        x4[0] = x4[0] + x3 * y1lo.x + x2ab * y2lo.x + x1a * y3lo.x + y4lo.x;
        x4[1] = x4[1] + x3 * y1lo.y + x2ab * y2lo.y + x1a * y3lo.y + y4lo.y;
        x4[2] = x4[2] + x3 * y1lo.z + x2ab * y2lo.z + x1a * y3lo.z + y4lo.z;
        x4[3] = x4[3] + x3 * y1lo.w + x2ab * y2lo.w + x1a * y3lo.w + y4lo.w;
        x4[4] = x4[4] + x3 * y1hi.x + x2ab * y2hi.x + x1a * y3hi.x + y4hi.x;
        x4[5] = x4[5] + x3 * y1hi.y + x2ab * y2hi.y + x1a * y3hi.y + y4hi.y;
        x4[6] = x4[6] + x3 * y1hi.z + x2ab * y2hi.z + x1a * y3hi.z + y4hi.z;
        x4[7] = x4[7] + x3 * y1hi.w + x2ab * y2hi.w + x1a * y3hi.w + y4hi.w;

        // new3[abc] = x3 + x2[ab]y1[c] + x1[a]y2[bc] + y3[abc]
        x3 = x3 + x2ab * y1c + x1a * y2bc + y3own;
        // new2[ab] = x2[ab] + x1[a]y1[b] + y2[ab]
        x2ab  = x2ab  + x1a * y1b + y2ab;
        // new2[bc] (output elem for tid<64) = x2[bc] + x1[b]y1[c] + y2[bc]
        x2own = x2own + x1b * y1c + y2bc;
        // new1
        x1a += y1a; x1b += y1b; x1c += y1c;
        (void)y1hi; // y1 row regs only needed via components above
    }

    float* o = out + (size_t)b * SIGSZ;
    if (tid < 8)  o[tid] = x1c;
    if (tid < 64) o[8 + tid] = x2own;
    o[72 + tid] = x3;
    *(float4*)(o + 584 + 8 * tid)     = make_float4(x4[0], x4[1], x4[2], x4[3]);
    *(float4*)(o + 584 + 8 * tid + 4) = make_float4(x4[4], x4[5], x4[6], x4[7]);
}

// ---------------- Fallback (round-1 kernel, used if ws too small) ----------------
__global__ __launch_bounds__(512)
void sig_fallback(const float* __restrict__ path, float* __restrict__ out) {
    const int b = blockIdx.x, tid = threadIdx.x;
    __shared__ float dxAll[Tc * 8];
    const float* prow = path + (size_t)b * Sc * 8;
    for (int n = tid; n < Tc * 8; n += 512) dxAll[n] = prow[n + 8] - prow[n];
    __syncthreads();

    const int aa = tid >> 6, bb = (tid >> 3) & 7, cc = tid & 7;
    float acc4[8] = {0.f,0.f,0.f,0.f,0.f,0.f,0.f,0.f};
    float acc3 = 0.f, s2ab = 0.f, acc2 = 0.f, s1a = 0.f, s1b = 0.f, s1c = 0.f;
    for (int t = 0; t < Tc; ++t) {
        const float* r = &dxAll[t * 8];
        float4 lo = *(const float4*)r;
        float4 hi = *(const float4*)(r + 4);
        float da = r[aa], db = r[bb], dc = r[cc];
        float e = db * dc;
        float K = acc3 + s2ab * (0.5f * dc) + e * fmaf(s1a, 1.f/6.f, da * (1.f/24.f));
        acc4[0] = fmaf(lo.x, K, acc4[0]);
        acc4[1] = fmaf(lo.y, K, acc4[1]);
        acc4[2] = fmaf(lo.z, K, acc4[2]);
        acc4[3] = fmaf(lo.w, K, acc4[3]);
        acc4[4] = fmaf(hi.x, K, acc4[4]);
        acc4[5] = fmaf(hi.y, K, acc4[5]);
        acc4[6] = fmaf(hi.z, K, acc4[6]);
        acc4[7] = fmaf(hi.w, K, acc4[7]);
        acc3 = acc3 + s2ab * dc + e * fmaf(0.5f, s1a, da * (1.f/6.f));
        acc2 = fmaf(s1b, dc, fmaf(0.5f, e, acc2));
        s2ab = fmaf(s1a, db, fmaf(0.5f * da, db, s2ab));
        s1a += da; s1b += db; s1c += dc;
    }
    float* o = out + (size_t)b * SIGSZ;
    if (tid < 8)  o[tid] = s1c;
    if (tid < 64) o[8 + tid] = acc2;
    o[72 + tid] = acc3;
    *(float4*)(o + 584 + 8 * tid)     = make_float4(acc4[0], acc4[1], acc4[2], acc4[3]);
    *(float4*)(o + 584 + 8 * tid + 4) = make_float4(acc4[4], acc4[5], acc4[6], acc4[7]);
}

extern "C" void kernel_launch(void* const* d_in, const int* in_sizes, int n_in,
                              void* d_out, int out_size, void* d_ws, size_t ws_size,
                              hipStream_t stream) {
    const float* path = (const float*)d_in[0];
    float* out = (float*)d_out;
    const size_t need = (size_t)Bc * NCH * SIGSZ * sizeof(float); // 19.2 MB
    if (ws_size >= need) {
        float* ws = (float*)d_ws;
        sig_chunk<<<dim3(Bc * NCH), dim3(512), 0, stream>>>(path, ws);
        sig_combine<<<dim3(Bc), dim3(512), 0, stream>>>(ws, out);
    } else {
        sig_fallback<<<dim3(Bc), dim3(512), 0, stream>>>(path, out);
    }
}

// Round 3
// 46.561 us; speedup vs baseline: 2.4107x; 1.0069x over previous
//
#include <hip/hip_runtime.h>

// Truncated path signature, trunc=4, D=8, B=128, S=512.
// Phase 0: dx precompute -> ws (padded to 512 rows/batch; row 511 = 0 = Chen identity).
// Phase 1: 128 batches x 8 chunks x 64 steps, one block (512 thr) each.
//          Barrier-free Chen recurrence; dx ROW comes from global via wave-uniform
//          address (VMEM/SMEM pipe), per-lane digit picks from LDS b32 broadcasts.
// Phase 2: 128 blocks fold the 8 chunk signatures (Chen product), unroll-2.
// Thread digits: aa=tid>>6 (wave-uniform), bb=(tid>>3)&7, cc=tid&7.

constexpr int Bc = 128, Sc = 512, Tc = 511;
constexpr int NCH = 8, CH = 64;
constexpr int SIGSZ = 8 + 64 + 512 + 4096;        // 4680 floats
constexpr int DXG_FLOATS = Bc * Sc * 8;           // 524288 floats (2 MiB), 16B-aligned
constexpr int SIG_OFF = DXG_FLOATS;               // sig chunks start here in ws

// ---------------- Phase 0: dx precompute ----------------
__global__ __launch_bounds__(256)
void dx_pre(const float* __restrict__ path, float* __restrict__ dxg) {
    int i = blockIdx.x * 256 + threadIdx.x;       // over Bc*Sc*8
    if (i >= DXG_FLOATS) return;
    int b = i >> 12;                              // / (Sc*8)
    int r = i & 4095;                             // t*8+j, t in [0,512)
    float v = 0.f;
    if (r < Tc * 8) {
        const float* p = path + ((size_t)b << 12);
        v = p[r + 8] - p[r];
    }
    dxg[i] = v;
}

// ---------------- Phase 1: per-chunk signature ----------------
__global__ __launch_bounds__(512, 8)
void sig_chunk(const float* __restrict__ dxg, float* __restrict__ ws) {
    const int blk = blockIdx.x;
    const int b   = blk >> 3;
    const int c   = blk & 7;
    const int tid = threadIdx.x;
    const int t0  = c * CH;

    const float* __restrict__ drow = dxg + (((size_t)b * Sc + t0) << 3); // uniform base
    __shared__ float dxs[CH * 8];                 // 2 KiB
    dxs[tid] = drow[tid];                         // 512 floats, coalesced
    __syncthreads();

    const int aa = tid >> 6, bb = (tid >> 3) & 7, cc = tid & 7;
    const bool low64 = (tid < 64);                // wave-uniform for waves 1..7

    float acc4[8] = {0.f,0.f,0.f,0.f,0.f,0.f,0.f,0.f};
    float acc3 = 0.f, s2ab = 0.f, acc2 = 0.f;
    float s1a = 0.f, s1b = 0.f, s1c = 0.f;

    const float4* __restrict__ dr4 = (const float4*)drow;

#pragma unroll 16
    for (int t = 0; t < CH; ++t) {
        float4 lo = dr4[2 * t];                   // wave-uniform address -> SMEM/VMEM pipe
        float4 hi = dr4[2 * t + 1];
        float da = dxs[t * 8 + aa];               // LDS b32 broadcasts (conflict-free)
        float db = dxs[t * 8 + bb];
        float dc = dxs[t * 8 + cc];

        float e = db * dc;
        float m = s2ab * dc;
        float v = fmaf(s1a, 1.f/6.f, da * (1.f/24.f));
        float K = fmaf(0.5f, m, acc3);
        K = fmaf(e, v, K);

        acc4[0] = fmaf(lo.x, K, acc4[0]);
        acc4[1] = fmaf(lo.y, K, acc4[1]);
        acc4[2] = fmaf(lo.z, K, acc4[2]);
        acc4[3] = fmaf(lo.w, K, acc4[3]);
        acc4[4] = fmaf(hi.x, K, acc4[4]);
        acc4[5] = fmaf(hi.y, K, acc4[5]);
        acc4[6] = fmaf(hi.z, K, acc4[6]);
        acc4[7] = fmaf(hi.w, K, acc4[7]);

        float w = fmaf(0.5f, s1a, da * (1.f/6.f));
        acc3 = acc3 + m;
        acc3 = fmaf(e, w, acc3);

        if (low64) {                              // only wave 0 pays for these
            acc2 = fmaf(s1b, dc, fmaf(0.5f, e, acc2));
            s1b += db; s1c += dc;
        }
        s2ab = fmaf(s1a, db, fmaf(0.5f * da, db, s2ab));
        s1a += da;
    }

    float* o = ws + SIG_OFF + (size_t)blk * SIGSZ;
    if (tid < 8)  o[tid] = s1c;
    if (tid < 64) o[8 + tid] = acc2;
    o[72 + tid] = acc3;
    *(float4*)(o + 584 + 8 * tid)     = make_float4(acc4[0], acc4[1], acc4[2], acc4[3]);
    *(float4*)(o + 584 + 8 * tid + 4) = make_float4(acc4[4], acc4[5], acc4[6], acc4[7]);
}

// ---------------- Phase 2: fold chunk signatures ----------------
__global__ __launch_bounds__(512)
void sig_combine(const float* __restrict__ ws, float* __restrict__ out) {
    const int b = blockIdx.x, tid = threadIdx.x;
    const int aa = tid >> 6, bb = (tid >> 3) & 7, cc = tid & 7;

    float x4[8] = {0.f,0.f,0.f,0.f,0.f,0.f,0.f,0.f};
    float x3 = 0.f, x2ab = 0.f, x2own = 0.f;
    float x1a = 0.f, x1b = 0.f, x1c = 0.f;

#pragma unroll 2
    for (int c = 0; c < NCH; ++c) {
        const float* y = ws + SIG_OFF + ((size_t)(b * NCH + c)) * SIGSZ;

        float y1a = y[aa], y1b = y[bb], y1c = y[cc];
        float4 y1lo = *(const float4*)y;
        float4 y1hi = *(const float4*)(y + 4);
        float y2ab = y[8 + 8 * aa + bb];
        float y2bc = y[8 + 8 * bb + cc];
        const float* y2r = y + 8 + 8 * cc;
        float4 y2lo = *(const float4*)y2r;
        float4 y2hi = *(const float4*)(y2r + 4);
        const float* y3r = y + 72 + 8 * (tid & 63);
        float4 y3lo = *(const float4*)y3r;
        float4 y3hi = *(const float4*)(y3r + 4);
        float y3own = y[72 + tid];
        const float* y4r = y + 584 + 8 * tid;
        float4 y4lo = *(const float4*)y4r;
        float4 y4hi = *(const float4*)(y4r + 4);

        x4[0] = x4[0] + x3 * y1lo.x + x2ab * y2lo.x + x1a * y3lo.x + y4lo.x;
        x4[1] = x4[1] + x3 * y1lo.y + x2ab * y2lo.y + x1a * y3lo.y + y4lo.y;
        x4[2] = x4[2] + x3 * y1lo.z + x2ab * y2lo.z + x1a * y3lo.z + y4lo.z;
        x4[3] = x4[3] + x3 * y1lo.w + x2ab * y2lo.w + x1a * y3lo.w + y4lo.w;
        x4[4] = x4[4] + x3 * y1hi.x + x2ab * y2hi.x + x1a * y3hi.x + y4hi.x;
        x4[5] = x4[5] + x3 * y1hi.y + x2ab * y2hi.y + x1a * y3hi.y + y4hi.y;
        x4[6] = x4[6] + x3 * y1hi.z + x2ab * y2hi.z + x1a * y3hi.z + y4hi.z;
        x4[7] = x4[7] + x3 * y1hi.w + x2ab * y2hi.w + x1a * y3hi.w + y4hi.w;

        x3 = x3 + x2ab * y1c + x1a * y2bc + y3own;
        x2ab  = x2ab  + x1a * y1b + y2ab;
        x2own = x2own + x1b * y1c + y2bc;
        x1a += y1a; x1b += y1b; x1c += y1c;
        (void)y1lo; (void)y1hi;
    }

    float* o = out + (size_t)b * SIGSZ;
    if (tid < 8)  o[tid] = x1c;
    if (tid < 64) o[8 + tid] = x2own;
    o[72 + tid] = x3;
    *(float4*)(o + 584 + 8 * tid)     = make_float4(x4[0], x4[1], x4[2], x4[3]);
    *(float4*)(o + 584 + 8 * tid + 4) = make_float4(x4[4], x4[5], x4[6], x4[7]);
}

// ---------------- Fallback (single-kernel, used if ws too small) ----------------
__global__ __launch_bounds__(512)
void sig_fallback(const float* __restrict__ path, float* __restrict__ out) {
    const int b = blockIdx.x, tid = threadIdx.x;
    __shared__ float dxAll[Tc * 8];
    const float* prow = path + (size_t)b * Sc * 8;
    for (int n = tid; n < Tc * 8; n += 512) dxAll[n] = prow[n + 8] - prow[n];
    __syncthreads();

    const int aa = tid >> 6, bb = (tid >> 3) & 7, cc = tid & 7;
    float acc4[8] = {0.f,0.f,0.f,0.f,0.f,0.f,0.f,0.f};
    float acc3 = 0.f, s2ab = 0.f, acc2 = 0.f, s1a = 0.f, s1b = 0.f, s1c = 0.f;
    for (int t = 0; t < Tc; ++t) {
        const float* r = &dxAll[t * 8];
        float4 lo = *(const float4*)r;
        float4 hi = *(const float4*)(r + 4);
        float da = r[aa], db = r[bb], dc = r[cc];
        float e = db * dc;
        float K = acc3 + s2ab * (0.5f * dc) + e * fmaf(s1a, 1.f/6.f, da * (1.f/24.f));
        acc4[0] = fmaf(lo.x, K, acc4[0]);
        acc4[1] = fmaf(lo.y, K, acc4[1]);
        acc4[2] = fmaf(lo.z, K, acc4[2]);
        acc4[3] = fmaf(lo.w, K, acc4[3]);
        acc4[4] = fmaf(hi.x, K, acc4[4]);
        acc4[5] = fmaf(hi.y, K, acc4[5]);
        acc4[6] = fmaf(hi.z, K, acc4[6]);
        acc4[7] = fmaf(hi.w, K, acc4[7]);
        acc3 = acc3 + s2ab * dc + e * fmaf(0.5f, s1a, da * (1.f/6.f));
        acc2 = fmaf(s1b, dc, fmaf(0.5f, e, acc2));
        s2ab = fmaf(s1a, db, fmaf(0.5f * da, db, s2ab));
        s1a += da; s1b += db; s1c += dc;
    }
    float* o = out + (size_t)b * SIGSZ;
    if (tid < 8)  o[tid] = s1c;
    if (tid < 64) o[8 + tid] = acc2;
    o[72 + tid] = acc3;
    *(float4*)(o + 584 + 8 * tid)     = make_float4(acc4[0], acc4[1], acc4[2], acc4[3]);
    *(float4*)(o + 584 + 8 * tid + 4) = make_float4(acc4[4], acc4[5], acc4[6], acc4[7]);
}

extern "C" void kernel_launch(void* const* d_in, const int* in_sizes, int n_in,
                              void* d_out, int out_size, void* d_ws, size_t ws_size,
                              hipStream_t stream) {
    const float* path = (const float*)d_in[0];
    float* out = (float*)d_out;
    const size_t need = (size_t)(DXG_FLOATS + Bc * NCH * SIGSZ) * sizeof(float); // ~21.3 MB
    if (ws_size >= need) {
        float* ws = (float*)d_ws;
        dx_pre   <<<dim3((DXG_FLOATS + 255) / 256), dim3(256), 0, stream>>>(path, ws);
        sig_chunk<<<dim3(Bc * NCH), dim3(512), 0, stream>>>(ws, ws);
        sig_combine<<<dim3(Bc), dim3(512), 0, stream>>>(ws, out);
    } else {
        sig_fallback<<<dim3(Bc), dim3(512), 0, stream>>>(path, out);
    }
}